// Round 13
// baseline (205.469 us; speedup 1.0000x reference)
//
#include <hip/hip_runtime.h>

#define B_ 2
#define S_ 2048
#define D_ 1024
#define H_ 16
#define HD_ 64
#define M_ (B_ * S_)   // 4096

typedef __attribute__((ext_vector_type(4))) float f32x4;
typedef __attribute__((ext_vector_type(16))) float f32x16;
typedef __attribute__((ext_vector_type(8))) short s16x8;
typedef unsigned short u16;
typedef unsigned int u32;

// 1/sqrt(64) * log2(e), folded into Wq at transpose time so attention softmax
// is a bare v_exp_f32.
#define QSCALE 0.1803368801111204f

__device__ __forceinline__ u16 f2bf(float f) {
  unsigned u = __float_as_uint(f);
  u += 0x7fffu + ((u >> 16) & 1u);
  return (u16)(u >> 16);
}

__device__ __forceinline__ u32 cvtpk_bf16(float lo, float hi) {
  u32 r;
  asm("v_cvt_pk_bf16_f32 %0, %1, %2" : "=v"(r) : "v"(lo), "v"(hi));
  return r;
}

__device__ __forceinline__ void g2lds16(const u16* g, u16* l) {
  __builtin_amdgcn_global_load_lds((const __attribute__((address_space(1))) u32*)(g),
                                   (__attribute__((address_space(3))) u32*)(l), 16, 0, 0);
}

// ---------------- fused: cast X (blocks 0..4095) + transpose-cast weights ----------------
__global__ __launch_bounds__(256) void prep_kernel(
    const float* __restrict__ X, const float* __restrict__ Wq,
    const float* __restrict__ Wk, const float* __restrict__ Wv,
    const float* __restrict__ Wo, u16* __restrict__ Xb, u16* __restrict__ Wt0) {
  __shared__ float tile[32][33];
  const int id = blockIdx.x;
  if (id < 4096) {
    int i = (id * 256 + threadIdx.x) * 4;
    const float4 v = *(const float4*)(X + i);
    ushort4 o;
    o.x = f2bf(v.x); o.y = f2bf(v.y); o.z = f2bf(v.z); o.w = f2bf(v.w);
    *(ushort4*)(Xb + i) = o;
    return;
  }
  const int id2 = id - 4096;
  const int z = id2 >> 10;
  const float* W = (z == 0) ? Wq : (z == 1) ? Wk : (z == 2) ? Wv : Wo;
  u16* Wt = Wt0 + (size_t)z * (D_ * D_);
  const float sc = (z == 0) ? QSCALE : 1.0f;
  const int tx = threadIdx.x & 31, ty = threadIdx.x >> 5;
  const int c0 = (id2 & 31) * 32, r0 = ((id2 >> 5) & 31) * 32;
#pragma unroll
  for (int j = 0; j < 32; j += 8)
    tile[ty + j][tx] = W[(size_t)(r0 + ty + j) * D_ + c0 + tx];
  __syncthreads();
#pragma unroll
  for (int j = 0; j < 32; j += 8)
    Wt[(size_t)(c0 + ty + j) * D_ + r0 + tx] = f2bf(tile[tx][ty + j] * sc);
}

// ---------------- QKV GEMM (round-6 proven), double-buffered, 1 barrier/K-step ----------------
__global__ __launch_bounds__(256) void gemm_qkv_kernel(
    const u16* __restrict__ Xb, const u16* __restrict__ WqT,
    const u16* __restrict__ WkT, const u16* __restrict__ WvT,
    u16* __restrict__ Qb, u16* __restrict__ Kb, u16* __restrict__ Vt) {
  __shared__ u16 As[2][128 * 32];
  __shared__ u16 Bs[2][128 * 32];
  const int tid = threadIdx.x;
  const int lane = tid & 63, wid = tid >> 6;
  const int wr = wid >> 1, wc = wid & 1;
  const int l15 = lane & 15, l4 = lane >> 4;
  const int bm = blockIdx.x * 128;
  const int bn128 = blockIdx.y;            // 0..23
  const int sel = bn128 >> 3;              // 0=Q 1=K 2=V
  const u16* Wt = (sel == 0) ? WqT : (sel == 1) ? WkT : WvT;
  const int bn = (bn128 & 7) * 128;
  const int r0 = lane >> 2;                // staging row within 16-row chunk
  const int c0 = lane & 3;                 // staging 16B chunk

#define GSTAGE(buf, kt)                                                          \
  do {                                                                           \
    _Pragma("unroll") for (int j = 0; j < 2; ++j) {                              \
      const int row = (wid * 2 + j) * 16 + r0;                                   \
      g2lds16(Xb + (size_t)(bm + row) * D_ + (kt) + c0 * 8,                      \
              &As[buf][(wid * 2 + j) * 512]);                                    \
      g2lds16(Wt + (size_t)(bn + row) * D_ + (kt) + c0 * 8,                      \
              &Bs[buf][(wid * 2 + j) * 512]);                                    \
    }                                                                            \
  } while (0)

  f32x4 acc[4][4] = {};
  GSTAGE(0, 0);
  __syncthreads();
  int cur = 0;
  for (int kt = 0; kt < D_; kt += 32) {
    GSTAGE(cur ^ 1, (kt + 32) & (D_ - 1));
    s16x8 af[4], bfr[4];
#pragma unroll
    for (int i = 0; i < 4; ++i) af[i] = *(const s16x8*)&As[cur][(wr * 64 + i * 16 + l15) * 32 + l4 * 8];
#pragma unroll
    for (int j = 0; j < 4; ++j) bfr[j] = *(const s16x8*)&Bs[cur][(wc * 64 + j * 16 + l15) * 32 + l4 * 8];
#pragma unroll
    for (int i = 0; i < 4; ++i)
#pragma unroll
      for (int j = 0; j < 4; ++j)
        acc[i][j] = __builtin_amdgcn_mfma_f32_16x16x32_bf16(af[i], bfr[j], acc[i][j], 0, 0, 0);
    __syncthreads();
    cur ^= 1;
  }
#undef GSTAGE
#pragma unroll
  for (int i = 0; i < 4; ++i)
#pragma unroll
    for (int j = 0; j < 4; ++j)
#pragma unroll
      for (int r = 0; r < 4; ++r) {
        int m = bm + wr * 64 + i * 16 + l4 * 4 + r;
        int n = bn + wc * 64 + j * 16 + l15;
        int bb = m >> 11, s = m & (S_ - 1);
        int h = n >> 6, d = n & 63;
        u16 v = f2bf(acc[i][j][r]);
        size_t bhsel = (size_t)bb * H_ + h;
        if (sel == 0)      Qb[(bhsel * S_ + s) * HD_ + d] = v;
        else if (sel == 1) Kb[(bhsel * S_ + s) * HD_ + d] = v;
        else               Vt[(bhsel * HD_ + d) * S_ + s] = v;
      }
}

// ---------------- flash attention: K via LDS, V direct from L2, ones-MFMA denom ----------------
// R11 structure (8 waves, KV-split halves, in-register P, lsacc on MFMA pipe)
// with V-staging dropped: per-(b,h) KV is L2-resident (XCD swizzle), so V's
// B-fragments are read straight from global into registers at tile start --
// halves LDS-pipe traffic and staging without touching occupancy. [m169 pattern]
__global__ __launch_bounds__(512, 4) void attn_kernel(
    const u16* __restrict__ Qb, const u16* __restrict__ Kb,
    const u16* __restrict__ Vt, u16* __restrict__ Ob) {
  __shared__ char smem_raw[51200];          // Ks 32 KB; merge buffer 50 KB (aliased)
  typedef u16 (*lds_t)[2][4096];
  lds_t Ks = (lds_t)smem_raw;               // [half][buf][64*64]
  const int tid = threadIdx.x;
  const int lane = tid & 63, wid = tid >> 6;   // wid 0..7
  const int qg = wid & 3, half = wid >> 2;
  const int l31 = lane & 31, hi = lane >> 5;
  // XCD swizzle: id%8 = XCD; each XCD owns 4 complete (b,h) -> KV L2-resident.
  const int id = blockIdx.x;
  const int bh = (id & 7) * 4 + ((id >> 3) >> 4);
  const int qx = (id >> 3) & 15;
  const size_t kbase = (size_t)bh * S_ * HD_;
  const size_t vbase = (size_t)bh * HD_ * S_;
  const int q0 = qx * 128 + qg * 32;            // this wave's 32 q-rows
  const int r0 = lane >> 3;                     // staging row within 8-row chunk
  const int cs = ((lane & 7) ^ r0) * 8;         // inverse-swizzled source offset
  const int kv0 = half << 10;                   // this half's key range base

#define STAGE(buf, kvv)                                                          \
  do {                                                                           \
    _Pragma("unroll") for (int j = 0; j < 2; ++j) {                              \
      const int row = (qg * 2 + j) * 8 + r0;                                     \
      g2lds16(Kb + kbase + (size_t)((kvv) + row) * HD_ + cs,                     \
              &Ks[half][buf][(qg * 2 + j) * 512]);                               \
    }                                                                            \
  } while (0)

  STAGE(0, kv0);

  // Q fragments (B-operand: col=q=l31, k = kc*16 + hi*8 + e); Wq pre-scaled.
  s16x8 aq[4];
#pragma unroll
  for (int kc = 0; kc < 4; ++kc)
    aq[kc] = *(const s16x8*)(Qb + kbase + (size_t)(q0 + l31) * HD_ + kc * 16 + hi * 8);

  // V row bases for this lane (B-operand rows d=l31 and d=32+l31)
  const u16* vrow0 = Vt + vbase + (size_t)l31 * S_;
  const u16* vrow1 = Vt + vbase + (size_t)(32 + l31) * S_;

  const short one_bf = (short)0x3F80;  // bf16 1.0
  const s16x8 ones8 = {one_bf, one_bf, one_bf, one_bf, one_bf, one_bf, one_bf, one_bf};

  f32x16 acc0 = {}, acc1 = {}, lsacc = {};

  int choff[4];
#pragma unroll
  for (int c = 0; c < 4; ++c) choff[c] = ((c * 2 + hi) ^ (l31 & 7)) * 8;

  __syncthreads();

  for (int t = 0; t < 16; ++t) {
    const int buf = t & 1;
    const int kvv = kv0 + (t << 6);
    STAGE(buf ^ 1, kv0 + (((t + 1) & 15) << 6));

    // ---- issue V register loads for THIS tile early (L2-hit latency hides
    //      under QK + exp + pack) ----
    s16x8 vr0[4], vr1[4];
#pragma unroll
    for (int c = 0; c < 4; ++c) {
      vr0[c] = *(const s16x8*)(vrow0 + kvv + c * 16 + hi * 8);
      vr1[c] = *(const s16x8*)(vrow1 + kvv + c * 16 + hi * 8);
    }

    // ---- QK^T: two 32-key blocks of this tile ----
    f32x16 s0 = {}, s1 = {};
    __builtin_amdgcn_s_setprio(1);
#pragma unroll
    for (int kc = 0; kc < 4; ++kc) {
      const s16x8 ka0 = *(const s16x8*)&Ks[half][buf][(l31) * 64 + choff[kc]];
      const s16x8 ka1 = *(const s16x8*)&Ks[half][buf][(32 + l31) * 64 + choff[kc]];
      s0 = __builtin_amdgcn_mfma_f32_32x32x16_bf16(ka0, aq[kc], s0, 0, 0, 0);
      s1 = __builtin_amdgcn_mfma_f32_32x32x16_bf16(ka1, aq[kc], s1, 0, 0, 0);
    }
    __builtin_amdgcn_s_setprio(0);

    // ---- softmax numerator: P = 2^s (denominator rides the MFMA pipe) ----
#pragma unroll
    for (int r = 0; r < 16; ++r) {
      s0[r] = __builtin_amdgcn_exp2f(s0[r]);
      s1[r] = __builtin_amdgcn_exp2f(s1[r]);
    }

    // ---- pack P into 32x32x16 A-frags: per 16-key chunk, 4 cvtpk + 2 swaps ----
    s16x8 pa[4];
#pragma unroll
    for (int c = 0; c < 4; ++c) {
      const int rr = (c & 1) * 8;
      u32 a0, a1, b0, b1;
      if (c < 2) {
        a0 = cvtpk_bf16(s0[rr + 0], s0[rr + 1]);
        a1 = cvtpk_bf16(s0[rr + 2], s0[rr + 3]);
        b0 = cvtpk_bf16(s0[rr + 4], s0[rr + 5]);
        b1 = cvtpk_bf16(s0[rr + 6], s0[rr + 7]);
      } else {
        a0 = cvtpk_bf16(s1[rr + 0], s1[rr + 1]);
        a1 = cvtpk_bf16(s1[rr + 2], s1[rr + 3]);
        b0 = cvtpk_bf16(s1[rr + 4], s1[rr + 5]);
        b1 = cvtpk_bf16(s1[rr + 6], s1[rr + 7]);
      }
      asm volatile("v_permlane32_swap_b32 %0, %1" : "+v"(a0), "+v"(b0));
      asm volatile("v_permlane32_swap_b32 %0, %1" : "+v"(a1), "+v"(b1));
      union { u32 u[4]; s16x8 v; } pk;
      pk.u[0] = a0; pk.u[1] = a1; pk.u[2] = b0; pk.u[3] = b1;
      pa[c] = pk.v;
    }

    // ---- PV + row-sum: O += P.V^T (V from registers); ls += P.ones ----
    __builtin_amdgcn_s_setprio(1);
#pragma unroll
    for (int c = 0; c < 4; ++c) {
      acc0 = __builtin_amdgcn_mfma_f32_32x32x16_bf16(pa[c], vr0[c], acc0, 0, 0, 0);
      acc1 = __builtin_amdgcn_mfma_f32_32x32x16_bf16(pa[c], vr1[c], acc1, 0, 0, 0);
      lsacc = __builtin_amdgcn_mfma_f32_32x32x16_bf16(pa[c], ones8, lsacc, 0, 0, 0);
    }
    __builtin_amdgcn_s_setprio(0);

    __syncthreads();
  }
#undef STAGE

  // ---- merge halves through LDS (partials are additive: no max-shift) ----
  float (*MB)[64][49] = (float(*)[64][49])smem_raw;
  if (half) {
#pragma unroll
    for (int r = 0; r < 16; ++r) {
      MB[qg][lane][r] = acc0[r];
      MB[qg][lane][16 + r] = acc1[r];
      MB[qg][lane][32 + r] = lsacc[r];
    }
  }
  __syncthreads();
  if (!half) {
    const int bb = bh >> 4, h = bh & 15;
#pragma unroll
    for (int r = 0; r < 16; ++r) {
      const float o0 = acc0[r] + MB[qg][lane][r];
      const float o1 = acc1[r] + MB[qg][lane][16 + r];
      const float rinv = 1.0f / (lsacc[r] + MB[qg][lane][32 + r]);
      const int qrow = (r & 3) + 8 * (r >> 2) + 4 * hi;
      const int q = q0 + qrow;
      Ob[(size_t)(bb * S_ + q) * (H_ * HD_) + h * HD_ + l31] = f2bf(o0 * rinv);
      Ob[(size_t)(bb * S_ + q) * (H_ * HD_) + h * HD_ + 32 + l31] = f2bf(o1 * rinv);
    }
  }
}

// ---------------- output projection GEMM + bias -> fp32, 128x64 tile, 2 blocks/CU ----------------
__global__ __launch_bounds__(256, 2) void gemm_o_kernel(
    const u16* __restrict__ A, const u16* __restrict__ Bt,
    const float* __restrict__ bias, float* __restrict__ C) {
  __shared__ u16 As[2][128 * 32];
  __shared__ u16 Bs[2][64 * 32];
  const int tid = threadIdx.x;
  const int lane = tid & 63, wid = tid >> 6;   // wid 0..3: 32-row strip each
  const int l15 = lane & 15, l4 = lane >> 4;
  const int bm = blockIdx.x * 128;
  const int bn = blockIdx.y * 64;
  const int r0 = lane >> 2;
  const int c0 = lane & 3;

#define GSTAGE(buf, kt)                                                          \
  do {                                                                           \
    _Pragma("unroll") for (int j = 0; j < 2; ++j) {                              \
      const int row = (wid * 2 + j) * 16 + r0;                                   \
      g2lds16(A + (size_t)(bm + row) * D_ + (kt) + c0 * 8,                       \
              &As[buf][(wid * 2 + j) * 512]);                                    \
    }                                                                            \
    g2lds16(Bt + (size_t)(bn + wid * 16 + r0) * D_ + (kt) + c0 * 8,              \
            &Bs[buf][wid * 512]);                                                \
  } while (0)

  f32x4 acc[2][4] = {};
  GSTAGE(0, 0);
  __syncthreads();
  int cur = 0;
  for (int kt = 0; kt < D_; kt += 32) {
    GSTAGE(cur ^ 1, (kt + 32) & (D_ - 1));
    s16x8 af[2], bfr[4];
#pragma unroll
    for (int i = 0; i < 2; ++i) af[i] = *(const s16x8*)&As[cur][(wid * 32 + i * 16 + l15) * 32 + l4 * 8];
#pragma unroll
    for (int j = 0; j < 4; ++j) bfr[j] = *(const s16x8*)&Bs[cur][(j * 16 + l15) * 32 + l4 * 8];
#pragma unroll
    for (int i = 0; i < 2; ++i)
#pragma unroll
      for (int j = 0; j < 4; ++j)
        acc[i][j] = __builtin_amdgcn_mfma_f32_16x16x32_bf16(af[i], bfr[j], acc[i][j], 0, 0, 0);
    __syncthreads();
    cur ^= 1;
  }
#undef GSTAGE
#pragma unroll
  for (int i = 0; i < 2; ++i)
#pragma unroll
    for (int j = 0; j < 4; ++j)
#pragma unroll
      for (int r = 0; r < 4; ++r) {
        int m = bm + wid * 32 + i * 16 + l4 * 4 + r;
        int n = bn + j * 16 + l15;
        C[(size_t)m * D_ + n] = acc[i][j][r] + bias[n];
      }
}

extern "C" void kernel_launch(void* const* d_in, const int* in_sizes, int n_in,
                              void* d_out, int out_size, void* d_ws, size_t ws_size,
                              hipStream_t stream) {
  const float* X  = (const float*)d_in[0];
  const float* Wq = (const float*)d_in[1];
  const float* Wk = (const float*)d_in[2];
  const float* Wv = (const float*)d_in[3];
  const float* Wo = (const float*)d_in[4];
  const float* bo = (const float*)d_in[5];
  float* out = (float*)d_out;

  char* w = (char*)d_ws;
  u16* Xb  = (u16*)(w);                      // 8 MB
  u16* WT  = (u16*)(w + (8u << 20));         // 4 x 2 MB: WqT,WkT,WvT,WoT contiguous
  u16* WqT = WT;
  u16* WkT = WT + (1u << 20);
  u16* WvT = WT + (2u << 20);
  u16* WoT = WT + (3u << 20);
  u16* Qb  = (u16*)(w + (16u << 20));        // 8 MB, [b][h][s][64] (pre-scaled)
  u16* Kb  = (u16*)(w + (24u << 20));        // 8 MB, [b][h][s][64]
  u16* Vt  = (u16*)(w + (32u << 20));        // 8 MB, [b][h][64][s]
  u16* Ob  = (u16*)(w + (40u << 20));        // 8 MB, [b*s][1024]

  prep_kernel<<<8192, 256, 0, stream>>>(X, Wq, Wk, Wv, Wo, Xb, WT);
  gemm_qkv_kernel<<<dim3(32, 24), 256, 0, stream>>>(Xb, WqT, WkT, WvT, Qb, Kb, Vt);
  attn_kernel<<<512, 512, 0, stream>>>(Qb, Kb, Vt, Ob);
  gemm_o_kernel<<<dim3(32, 16), 256, 0, stream>>>(Ob, WoT, bo, out);
}

// Round 14
// 118.062 us; speedup vs baseline: 1.7404x; 1.7404x over previous
//
#include <hip/hip_runtime.h>

#define B_ 2
#define S_ 2048
#define D_ 1024
#define H_ 16
#define HD_ 64
#define M_ (B_ * S_)   // 4096

typedef __attribute__((ext_vector_type(4))) float f32x4;
typedef __attribute__((ext_vector_type(16))) float f32x16;
typedef __attribute__((ext_vector_type(8))) short s16x8;
typedef unsigned short u16;
typedef unsigned int u32;

// 1/sqrt(64) * log2(e), folded into Wq at transpose time so attention softmax
// is a bare v_exp_f32.
#define QSCALE 0.1803368801111204f

__device__ __forceinline__ u16 f2bf(float f) {
  unsigned u = __float_as_uint(f);
  u += 0x7fffu + ((u >> 16) & 1u);
  return (u16)(u >> 16);
}

__device__ __forceinline__ u32 cvtpk_bf16(float lo, float hi) {
  u32 r;
  asm("v_cvt_pk_bf16_f32 %0, %1, %2" : "=v"(r) : "v"(lo), "v"(hi));
  return r;
}

__device__ __forceinline__ void g2lds16(const u16* g, u16* l) {
  __builtin_amdgcn_global_load_lds((const __attribute__((address_space(1))) u32*)(g),
                                   (__attribute__((address_space(3))) u32*)(l), 16, 0, 0);
}

// ---------------- fused: cast X (blocks 0..4095) + transpose-cast weights ----------------
__global__ __launch_bounds__(256) void prep_kernel(
    const float* __restrict__ X, const float* __restrict__ Wq,
    const float* __restrict__ Wk, const float* __restrict__ Wv,
    const float* __restrict__ Wo, u16* __restrict__ Xb, u16* __restrict__ Wt0) {
  __shared__ float tile[32][33];
  const int id = blockIdx.x;
  if (id < 4096) {
    int i = (id * 256 + threadIdx.x) * 4;
    const float4 v = *(const float4*)(X + i);
    ushort4 o;
    o.x = f2bf(v.x); o.y = f2bf(v.y); o.z = f2bf(v.z); o.w = f2bf(v.w);
    *(ushort4*)(Xb + i) = o;
    return;
  }
  const int id2 = id - 4096;
  const int z = id2 >> 10;
  const float* W = (z == 0) ? Wq : (z == 1) ? Wk : (z == 2) ? Wv : Wo;
  u16* Wt = Wt0 + (size_t)z * (D_ * D_);
  const float sc = (z == 0) ? QSCALE : 1.0f;
  const int tx = threadIdx.x & 31, ty = threadIdx.x >> 5;
  const int c0 = (id2 & 31) * 32, r0 = ((id2 >> 5) & 31) * 32;
#pragma unroll
  for (int j = 0; j < 32; j += 8)
    tile[ty + j][tx] = W[(size_t)(r0 + ty + j) * D_ + c0 + tx];
  __syncthreads();
#pragma unroll
  for (int j = 0; j < 32; j += 8)
    Wt[(size_t)(c0 + ty + j) * D_ + r0 + tx] = f2bf(tile[tx][ty + j] * sc);
}

// ---------------- QKV GEMM (round-6 proven), double-buffered, 1 barrier/K-step ----------------
__global__ __launch_bounds__(256) void gemm_qkv_kernel(
    const u16* __restrict__ Xb, const u16* __restrict__ WqT,
    const u16* __restrict__ WkT, const u16* __restrict__ WvT,
    u16* __restrict__ Qb, u16* __restrict__ Kb, u16* __restrict__ Vt) {
  __shared__ u16 As[2][128 * 32];
  __shared__ u16 Bs[2][128 * 32];
  const int tid = threadIdx.x;
  const int lane = tid & 63, wid = tid >> 6;
  const int wr = wid >> 1, wc = wid & 1;
  const int l15 = lane & 15, l4 = lane >> 4;
  const int bm = blockIdx.x * 128;
  const int bn128 = blockIdx.y;            // 0..23
  const int sel = bn128 >> 3;              // 0=Q 1=K 2=V
  const u16* Wt = (sel == 0) ? WqT : (sel == 1) ? WkT : WvT;
  const int bn = (bn128 & 7) * 128;
  const int r0 = lane >> 2;                // staging row within 16-row chunk
  const int c0 = lane & 3;                 // staging 16B chunk

#define GSTAGE(buf, kt)                                                          \
  do {                                                                           \
    _Pragma("unroll") for (int j = 0; j < 2; ++j) {                              \
      const int row = (wid * 2 + j) * 16 + r0;                                   \
      g2lds16(Xb + (size_t)(bm + row) * D_ + (kt) + c0 * 8,                      \
              &As[buf][(wid * 2 + j) * 512]);                                    \
      g2lds16(Wt + (size_t)(bn + row) * D_ + (kt) + c0 * 8,                      \
              &Bs[buf][(wid * 2 + j) * 512]);                                    \
    }                                                                            \
  } while (0)

  f32x4 acc[4][4] = {};
  GSTAGE(0, 0);
  __syncthreads();
  int cur = 0;
  for (int kt = 0; kt < D_; kt += 32) {
    GSTAGE(cur ^ 1, (kt + 32) & (D_ - 1));
    s16x8 af[4], bfr[4];
#pragma unroll
    for (int i = 0; i < 4; ++i) af[i] = *(const s16x8*)&As[cur][(wr * 64 + i * 16 + l15) * 32 + l4 * 8];
#pragma unroll
    for (int j = 0; j < 4; ++j) bfr[j] = *(const s16x8*)&Bs[cur][(wc * 64 + j * 16 + l15) * 32 + l4 * 8];
#pragma unroll
    for (int i = 0; i < 4; ++i)
#pragma unroll
      for (int j = 0; j < 4; ++j)
        acc[i][j] = __builtin_amdgcn_mfma_f32_16x16x32_bf16(af[i], bfr[j], acc[i][j], 0, 0, 0);
    __syncthreads();
    cur ^= 1;
  }
#undef GSTAGE
#pragma unroll
  for (int i = 0; i < 4; ++i)
#pragma unroll
    for (int j = 0; j < 4; ++j)
#pragma unroll
      for (int r = 0; r < 4; ++r) {
        int m = bm + wr * 64 + i * 16 + l4 * 4 + r;
        int n = bn + wc * 64 + j * 16 + l15;
        int bb = m >> 11, s = m & (S_ - 1);
        int h = n >> 6, d = n & 63;
        u16 v = f2bf(acc[i][j][r]);
        size_t bhsel = (size_t)bb * H_ + h;
        if (sel == 0)      Qb[(bhsel * S_ + s) * HD_ + d] = v;
        else if (sel == 1) Kb[(bhsel * S_ + s) * HD_ + d] = v;
        else               Vt[(bhsel * HD_ + d) * S_ + s] = v;
      }
}

// ---------------- flash attention: counted-vmcnt pipeline, 3-deep KV ring ----------------
// 4 waves/block, each owning 32 q-rows x ALL 2048 keys (32 tiles of 64).
// Iter t: stage tile t+2 into ring slot b2, compute tile t from slot b0; the
// end-of-tile sync is s_waitcnt vmcnt(4) + raw s_barrier -- only tile t+1's 4
// loads must have landed; tile t+2's loads stay in flight ACROSS the barrier
// (T4: never drain vmcnt to 0 in the main loop). WAR safe: slot b2 was last
// read at iter t-1, protected by that iteration's barrier. Denominator rides
// the MFMA pipe (ones-MFMA). No half-merge epilogue.
__global__ __launch_bounds__(256, 2) void attn_kernel(
    const u16* __restrict__ Qb, const u16* __restrict__ Kb,
    const u16* __restrict__ Vt, u16* __restrict__ Ob) {
  __shared__ u16 Ks[3][4096];
  __shared__ u16 Vs[3][4096];
  const int tid = threadIdx.x;
  const int lane = tid & 63, wid = tid >> 6;   // wid 0..3
  const int l31 = lane & 31, hi = lane >> 5;
  // XCD swizzle: id%8 = XCD; each XCD owns 4 complete (b,h) -> KV L2-resident.
  const int id = blockIdx.x;
  const int bh = (id & 7) * 4 + ((id >> 3) >> 4);
  const int qx = (id >> 3) & 15;
  const size_t kbase = (size_t)bh * S_ * HD_;
  const size_t vbase = (size_t)bh * HD_ * S_;
  const int q0 = qx * 128 + wid * 32;           // this wave's 32 q-rows
  const int r0 = lane >> 3;                     // staging row within 8-row chunk
  const int cs = ((lane & 7) ^ r0) * 8;         // inverse-swizzled source offset

#define STAGE(b, kvv)                                                            \
  do {                                                                           \
    _Pragma("unroll") for (int j = 0; j < 2; ++j) {                              \
      const int row = (wid * 2 + j) * 8 + r0;                                    \
      g2lds16(Kb + kbase + (size_t)((kvv) + row) * HD_ + cs,                     \
              &Ks[b][(wid * 2 + j) * 512]);                                      \
      g2lds16(Vt + vbase + (size_t)row * S_ + (kvv) + cs,                        \
              &Vs[b][(wid * 2 + j) * 512]);                                      \
    }                                                                            \
  } while (0)

  // Q fragments FIRST (oldest in vmcnt queue so the compiler's wait for them
  // does not drain the staging prefetches). B-operand: col=q=l31, k=kc*16+hi*8+e.
  s16x8 aq[4];
#pragma unroll
  for (int kc = 0; kc < 4; ++kc)
    aq[kc] = *(const s16x8*)(Qb + kbase + (size_t)(q0 + l31) * HD_ + kc * 16 + hi * 8);

  STAGE(0, 0);
  STAGE(1, 64);

  const short one_bf = (short)0x3F80;  // bf16 1.0
  const s16x8 ones8 = {one_bf, one_bf, one_bf, one_bf, one_bf, one_bf, one_bf, one_bf};

  f32x16 acc0 = {}, acc1 = {}, lsacc = {};

  int choff[4];
#pragma unroll
  for (int c = 0; c < 4; ++c) choff[c] = ((c * 2 + hi) ^ (l31 & 7)) * 8;

  // wait for tile 0 (oldest 4+aq), leave tile 1 in flight
  asm volatile("s_waitcnt vmcnt(4)" ::: "memory");
  __builtin_amdgcn_s_barrier();
  __builtin_amdgcn_sched_barrier(0);

  int b0 = 0, b1 = 1, b2 = 2;
#pragma unroll 1
  for (int t = 0; t < 32; ++t) {
    STAGE(b2, ((t + 2) & 31) << 6);

    // ---- QK^T: two 32-key blocks of this tile ----
    f32x16 s0 = {}, s1 = {};
    __builtin_amdgcn_s_setprio(1);
#pragma unroll
    for (int kc = 0; kc < 4; ++kc) {
      const s16x8 ka0 = *(const s16x8*)&Ks[b0][(l31) * 64 + choff[kc]];
      const s16x8 ka1 = *(const s16x8*)&Ks[b0][(32 + l31) * 64 + choff[kc]];
      s0 = __builtin_amdgcn_mfma_f32_32x32x16_bf16(ka0, aq[kc], s0, 0, 0, 0);
      s1 = __builtin_amdgcn_mfma_f32_32x32x16_bf16(ka1, aq[kc], s1, 0, 0, 0);
    }
    __builtin_amdgcn_s_setprio(0);

    // ---- softmax numerator: P = 2^s (denominator rides the MFMA pipe) ----
#pragma unroll
    for (int r = 0; r < 16; ++r) {
      s0[r] = __builtin_amdgcn_exp2f(s0[r]);
      s1[r] = __builtin_amdgcn_exp2f(s1[r]);
    }

    // ---- pack P into 32x32x16 A-frags: per 16-key chunk, 4 cvtpk + 2 swaps ----
    s16x8 pa[4];
#pragma unroll
    for (int c = 0; c < 4; ++c) {
      const int rr = (c & 1) * 8;
      u32 a0, a1, b0_, b1_;
      if (c < 2) {
        a0 = cvtpk_bf16(s0[rr + 0], s0[rr + 1]);
        a1 = cvtpk_bf16(s0[rr + 2], s0[rr + 3]);
        b0_ = cvtpk_bf16(s0[rr + 4], s0[rr + 5]);
        b1_ = cvtpk_bf16(s0[rr + 6], s0[rr + 7]);
      } else {
        a0 = cvtpk_bf16(s1[rr + 0], s1[rr + 1]);
        a1 = cvtpk_bf16(s1[rr + 2], s1[rr + 3]);
        b0_ = cvtpk_bf16(s1[rr + 4], s1[rr + 5]);
        b1_ = cvtpk_bf16(s1[rr + 6], s1[rr + 7]);
      }
      asm volatile("v_permlane32_swap_b32 %0, %1" : "+v"(a0), "+v"(b0_));
      asm volatile("v_permlane32_swap_b32 %0, %1" : "+v"(a1), "+v"(b1_));
      union { u32 u[4]; s16x8 v; } pk;
      pk.u[0] = a0; pk.u[1] = a1; pk.u[2] = b0_; pk.u[3] = b1_;
      pa[c] = pk.v;
    }

    // ---- PV + row-sum: O += P.V^T ; ls += P.ones ----
    __builtin_amdgcn_s_setprio(1);
#pragma unroll
    for (int c = 0; c < 4; ++c) {
      const s16x8 vb0 = *(const s16x8*)&Vs[b0][(l31) * 64 + choff[c]];
      const s16x8 vb1 = *(const s16x8*)&Vs[b0][(32 + l31) * 64 + choff[c]];
      acc0 = __builtin_amdgcn_mfma_f32_32x32x16_bf16(pa[c], vb0, acc0, 0, 0, 0);
      acc1 = __builtin_amdgcn_mfma_f32_32x32x16_bf16(pa[c], vb1, acc1, 0, 0, 0);
      lsacc = __builtin_amdgcn_mfma_f32_32x32x16_bf16(pa[c], ones8, lsacc, 0, 0, 0);
    }
    __builtin_amdgcn_s_setprio(0);

    // counted sync: tile t+1's 4 loads must be done; t+2's may remain in flight
    asm volatile("s_waitcnt vmcnt(4)" ::: "memory");
    __builtin_amdgcn_s_barrier();
    __builtin_amdgcn_sched_barrier(0);

    const int tmp = b0; b0 = b1; b1 = b2; b2 = tmp;
  }
#undef STAGE

  // ---- epilogue: normalize and write (no merge needed) ----
  const int bb = bh >> 4, h = bh & 15;
#pragma unroll
  for (int r = 0; r < 16; ++r) {
    const float rinv = 1.0f / lsacc[r];
    const int qrow = (r & 3) + 8 * (r >> 2) + 4 * hi;
    const int q = q0 + qrow;
    Ob[(size_t)(bb * S_ + q) * (H_ * HD_) + h * HD_ + l31] = f2bf(acc0[r] * rinv);
    Ob[(size_t)(bb * S_ + q) * (H_ * HD_) + h * HD_ + 32 + l31] = f2bf(acc1[r] * rinv);
  }
}

// ---------------- output projection GEMM + bias -> fp32, 128x64 tile, 2 blocks/CU ----------------
__global__ __launch_bounds__(256, 2) void gemm_o_kernel(
    const u16* __restrict__ A, const u16* __restrict__ Bt,
    const float* __restrict__ bias, float* __restrict__ C) {
  __shared__ u16 As[2][128 * 32];
  __shared__ u16 Bs[2][64 * 32];
  const int tid = threadIdx.x;
  const int lane = tid & 63, wid = tid >> 6;   // wid 0..3: 32-row strip each
  const int l15 = lane & 15, l4 = lane >> 4;
  const int bm = blockIdx.x * 128;
  const int bn = blockIdx.y * 64;
  const int r0 = lane >> 2;
  const int c0 = lane & 3;

#define GSTAGE(buf, kt)                                                          \
  do {                                                                           \
    _Pragma("unroll") for (int j = 0; j < 2; ++j) {                              \
      const int row = (wid * 2 + j) * 16 + r0;                                   \
      g2lds16(A + (size_t)(bm + row) * D_ + (kt) + c0 * 8,                       \
              &As[buf][(wid * 2 + j) * 512]);                                    \
    }                                                                            \
    g2lds16(Bt + (size_t)(bn + wid * 16 + r0) * D_ + (kt) + c0 * 8,              \
            &Bs[buf][wid * 512]);                                                \
  } while (0)

  f32x4 acc[2][4] = {};
  GSTAGE(0, 0);
  __syncthreads();
  int cur = 0;
  for (int kt = 0; kt < D_; kt += 32) {
    GSTAGE(cur ^ 1, (kt + 32) & (D_ - 1));
    s16x8 af[2], bfr[4];
#pragma unroll
    for (int i = 0; i < 2; ++i) af[i] = *(const s16x8*)&As[cur][(wid * 32 + i * 16 + l15) * 32 + l4 * 8];
#pragma unroll
    for (int j = 0; j < 4; ++j) bfr[j] = *(const s16x8*)&Bs[cur][(j * 16 + l15) * 32 + l4 * 8];
#pragma unroll
    for (int i = 0; i < 2; ++i)
#pragma unroll
      for (int j = 0; j < 4; ++j)
        acc[i][j] = __builtin_amdgcn_mfma_f32_16x16x32_bf16(af[i], bfr[j], acc[i][j], 0, 0, 0);
    __syncthreads();
    cur ^= 1;
  }
#undef GSTAGE
#pragma unroll
  for (int i = 0; i < 2; ++i)
#pragma unroll
    for (int j = 0; j < 4; ++j)
#pragma unroll
      for (int r = 0; r < 4; ++r) {
        int m = bm + wid * 32 + i * 16 + l4 * 4 + r;
        int n = bn + j * 16 + l15;
        C[(size_t)m * D_ + n] = acc[i][j][r] + bias[n];
      }
}

extern "C" void kernel_launch(void* const* d_in, const int* in_sizes, int n_in,
                              void* d_out, int out_size, void* d_ws, size_t ws_size,
                              hipStream_t stream) {
  const float* X  = (const float*)d_in[0];
  const float* Wq = (const float*)d_in[1];
  const float* Wk = (const float*)d_in[2];
  const float* Wv = (const float*)d_in[3];
  const float* Wo = (const float*)d_in[4];
  const float* bo = (const float*)d_in[5];
  float* out = (float*)d_out;

  char* w = (char*)d_ws;
  u16* Xb  = (u16*)(w);                      // 8 MB
  u16* WT  = (u16*)(w + (8u << 20));         // 4 x 2 MB: WqT,WkT,WvT,WoT contiguous
  u16* WqT = WT;
  u16* WkT = WT + (1u << 20);
  u16* WvT = WT + (2u << 20);
  u16* WoT = WT + (3u << 20);
  u16* Qb  = (u16*)(w + (16u << 20));        // 8 MB, [b][h][s][64] (pre-scaled)
  u16* Kb  = (u16*)(w + (24u << 20));        // 8 MB, [b][h][s][64]
  u16* Vt  = (u16*)(w + (32u << 20));        // 8 MB, [b][h][64][s]
  u16* Ob  = (u16*)(w + (40u << 20));        // 8 MB, [b*s][1024]

  prep_kernel<<<8192, 256, 0, stream>>>(X, Wq, Wk, Wv, Wo, Xb, WT);
  gemm_qkv_kernel<<<dim3(32, 24), 256, 0, stream>>>(Xb, WqT, WkT, WvT, Qb, Kb, Vt);
  attn_kernel<<<512, 256, 0, stream>>>(Qb, Kb, Vt, Ob);
  gemm_o_kernel<<<dim3(32, 16), 256, 0, stream>>>(Ob, WoT, bo, out);
}